// Round 13
// baseline (514.523 us; speedup 1.0000x reference)
//
#include <hip/hip_runtime.h>
#include <hip/hip_bf16.h>

#define T_TOK 2048
#define H_DIM 2048
#define E_NUM 32
#define I_DIM 768
#define TOPK  4
#define S4    (T_TOK * TOPK)          // 8192 slots
#define GU_IMG 8192                   // u16 per (e,nt,c) gateup image = 16KB
#define DN_IMG 8192                   // u16 per (e,nt,c) down image  = 16KB

typedef __attribute__((ext_vector_type(8))) short bf16x8;
typedef __attribute__((ext_vector_type(4))) float f32x4;

__device__ __forceinline__ unsigned pk2(float a, float b) {
    __hip_bfloat16 ha = __float2bfloat16(a);
    __hip_bfloat16 hb = __float2bfloat16(b);
    unsigned short ua = *(unsigned short*)&ha;
    unsigned short ub = *(unsigned short*)&hb;
    return (unsigned)ua | ((unsigned)ub << 16);
}

__device__ __forceinline__ void gld16(const void* g, void* l) {
    __builtin_amdgcn_global_load_lds(
        (const __attribute__((address_space(1))) void*)g,
        (__attribute__((address_space(3))) void*)l, 16, 0, 0);
}

#define MFMA16(a, b, c) __builtin_amdgcn_mfma_f32_16x16x32_bf16(a, b, c, 0, 0, 0)

// ---------------- Router ----------------
__global__ __launch_bounds__(64) void router_kernel(
    const float* __restrict__ x, const float* __restrict__ gate_w,
    float* __restrict__ logits_out, int* __restrict__ cnt,
    int* __restrict__ tok_list, float* __restrict__ tok_w,
    int* __restrict__ tok_slots)
{
    const int t = blockIdx.x;
    const int lane = threadIdx.x;
    __shared__ float xs[H_DIM];
    const float4* __restrict__ xv = (const float4*)(x + (size_t)t * H_DIM);
    float4* xsv = (float4*)xs;
#pragma unroll
    for (int i = 0; i < H_DIM / 4 / 64; ++i) xsv[lane + i * 64] = xv[lane + i * 64];
    __syncthreads();

    const int e = lane & 31;
    const int half = lane >> 5;
    const float4* __restrict__ wv = (const float4*)(gate_w + (size_t)e * H_DIM) + half * (H_DIM / 8);
    const float4* __restrict__ xh = ((const float4*)xs) + half * (H_DIM / 8);
    float acc = 0.f;
#pragma unroll 4
    for (int i = 0; i < H_DIM / 8; ++i) {
        float4 w4 = wv[i], x4 = xh[i];
        acc += w4.x * x4.x + w4.y * x4.y + w4.z * x4.z + w4.w * x4.w;
    }
    acc += __shfl_xor(acc, 32, 64);
    if (lane < 32) logits_out[(size_t)t * E_NUM + e] = acc;

    float v = acc;
    float topv[TOPK]; int topi[TOPK];
#pragma unroll
    for (int r = 0; r < TOPK; ++r) {
        float bv = v; int bi = e;
#pragma unroll
        for (int off = 16; off >= 1; off >>= 1) {
            float ov = __shfl_xor(bv, off, 32);
            int   oi = __shfl_xor(bi, off, 32);
            if (ov > bv || (ov == bv && oi < bi)) { bv = ov; bi = oi; }
        }
        topv[r] = bv; topi[r] = bi;
        if (e == bi) v = -1e30f;
    }
    if (lane == 0) {
        float w[TOPK]; float s = 0.f;
#pragma unroll
        for (int r = 0; r < TOPK; ++r) { w[r] = expf(topv[r] - topv[0]); s += w[r]; }
        float inv = 1.f / s;
#pragma unroll
        for (int r = 0; r < TOPK; ++r) {
            int pos = atomicAdd(&cnt[topi[r]], 1);
            tok_list[topi[r] * T_TOK + pos] = t;
            tok_w  [topi[r] * T_TOK + pos] = w[r] * inv;
            tok_slots[t * TOPK + r] = (topi[r] << 12) | pos;
        }
    }
}

__global__ void scan_kernel(const int* __restrict__ cnt, int* __restrict__ slot_base)
{
    if (threadIdx.x == 0) {
        int s = 0;
        for (int e = 0; e < E_NUM; ++e) { slot_base[e] = s; s += cnt[e]; }
        slot_base[E_NUM] = s;
    }
}

// ------- Pack gup_w -> bf16 GEMM-native images [e][nt][c][half][kk][n32][8] -----
// block (e, kg): 8 full rows k=kg*8..+7 (coalesced 6KB reads), LDS transpose,
// contiguous 16B-granule writes.
__global__ __launch_bounds__(256) void pack_gu(
    const float* __restrict__ gup_w, unsigned short* __restrict__ pgu)
{
    const int e  = blockIdx.x;
    const int kg = blockIdx.y;               // 0..255
    const int c  = kg >> 4, kk = kg & 15;
    __shared__ unsigned short ls[8][1538];   // +2 pad
    const float* __restrict__ src = gup_w + ((size_t)e * H_DIM + kg * 8) * (2 * I_DIM);
#pragma unroll
    for (int r = 0; r < 8; ++r) {
        const float4* s4 = (const float4*)(src + (size_t)r * (2 * I_DIM));
        for (int i = threadIdx.x; i < (2 * I_DIM) / 4; i += 256) {
            float4 v = s4[i];
            *(unsigned*)&ls[r][i * 4]     = pk2(v.x, v.y);
            *(unsigned*)&ls[r][i * 4 + 2] = pk2(v.z, v.w);
        }
    }
    __syncthreads();
    for (int g = threadIdx.x; g < 2 * I_DIM; g += 256) {
        const int half = g >= I_DIM;
        const int cg = g - half * I_DIM;
        const int nt = cg >> 5, n = cg & 31;
        uint4 o;
        o.x = (unsigned)ls[0][g] | ((unsigned)ls[1][g] << 16);
        o.y = (unsigned)ls[2][g] | ((unsigned)ls[3][g] << 16);
        o.z = (unsigned)ls[4][g] | ((unsigned)ls[5][g] << 16);
        o.w = (unsigned)ls[6][g] | ((unsigned)ls[7][g] << 16);
        unsigned short* dst = pgu + ((size_t)(e * 24 + nt) * 16 + c) * GU_IMG
                            + ((half * 16 + kk) * 32 + n) * 8;
        *(uint4*)dst = o;
    }
}

// ------- Pack down_w -> bf16 images [e][nt][c][kk][n64][8] -----
__global__ __launch_bounds__(256) void pack_dn(
    const float* __restrict__ down_w, unsigned short* __restrict__ pdn)
{
    const int e  = blockIdx.x;
    const int kg = blockIdx.y;               // 0..95
    const int c  = kg >> 4, kk = kg & 15;
    __shared__ unsigned short ls[8][2050];   // +2 pad
    const float* __restrict__ src = down_w + ((size_t)e * I_DIM + kg * 8) * H_DIM;
#pragma unroll
    for (int r = 0; r < 8; ++r) {
        const float4* s4 = (const float4*)(src + (size_t)r * H_DIM);
        for (int i = threadIdx.x; i < H_DIM / 4; i += 256) {
            float4 v = s4[i];
            *(unsigned*)&ls[r][i * 4]     = pk2(v.x, v.y);
            *(unsigned*)&ls[r][i * 4 + 2] = pk2(v.z, v.w);
        }
    }
    __syncthreads();
    for (int g = threadIdx.x; g < H_DIM; g += 256) {
        const int nt = g >> 6, n = g & 63;
        uint4 o;
        o.x = (unsigned)ls[0][g] | ((unsigned)ls[1][g] << 16);
        o.y = (unsigned)ls[2][g] | ((unsigned)ls[3][g] << 16);
        o.z = (unsigned)ls[4][g] | ((unsigned)ls[5][g] << 16);
        o.w = (unsigned)ls[6][g] | ((unsigned)ls[7][g] << 16);
        unsigned short* dst = pdn + ((size_t)(e * 32 + nt) * 6 + c) * DN_IMG
                            + (kk * 64 + n) * 8;
        *(uint4*)dst = o;
    }
}

// ------- Gather tokens per expert, convert x -> bf16 in K-PANEL layout -------
__global__ __launch_bounds__(256) void gather_kernel(
    const float* __restrict__ x, const int* __restrict__ cnt,
    const int* __restrict__ slot_base, const int* __restrict__ tok_list,
    unsigned short* __restrict__ xg_t)
{
    const int e = blockIdx.x;
    const int count = cnt[e];
    const int m0 = blockIdx.y * 8;
    if (m0 >= count) return;
    const int s8   = threadIdx.x >> 5;
    const int kc31 = threadIdx.x & 31;
    const int m = m0 + s8;
    if (m >= count) return;
    const int tok  = tok_list[e * T_TOK + m];
    const int slot = slot_base[e] + m;
    const float* __restrict__ src = x + (size_t)tok * H_DIM;
#pragma unroll
    for (int kcq = 0; kcq < 8; ++kcq) {
        const int kc = kcq * 32 + kc31;
        float4 a = *(const float4*)(src + kc * 8);
        float4 b = *(const float4*)(src + kc * 8 + 4);
        uint4 o;
        o.x = pk2(a.x, a.y); o.y = pk2(a.z, a.w);
        o.z = pk2(b.x, b.y); o.w = pk2(b.z, b.w);
        *(uint4*)(xg_t + ((size_t)kc * S4 + slot) * 8) = o;
    }
}

// ---------------- gate_up MFMA + silu + weight-scale -> h_t (panel bf16) -----
// tile 256(M) x 32(g)+32(u); A reg-direct; B gld16-staged from packed images.
#define GU_NC (H_DIM / 128)   // 16 chunks
__global__ __launch_bounds__(512, 4) void gateup_mfma(
    const unsigned short* __restrict__ xg_t, const unsigned short* __restrict__ pgu,
    const int* __restrict__ cnt, const int* __restrict__ slot_base,
    const float* __restrict__ tok_w, unsigned short* __restrict__ h_t)
{
    const int e  = blockIdx.x;
    const int nt = blockIdx.y;
    const int mt = blockIdx.z;
    const int count = cnt[e];
    if (mt * 256 >= count) return;
    const int tid  = threadIdx.x;
    const int lane = tid & 63;
    const int w    = tid >> 6;
    const int base = slot_base[e];
    const int l16  = lane & 15, lg = lane >> 4;

    __shared__ unsigned short Bls[2][GU_IMG];   // [buf][half][kk][n32][8] 32KB
    __shared__ float wls[256];                  // 1KB

    if (tid < 256) {
        int m = mt * 256 + tid; if (m >= count) m = count - 1;
        wls[tid] = tok_w[e * T_TOK + m];
    }

    int m0 = mt * 256 + w * 32 + l16;      if (m0 >= count) m0 = count - 1;
    int m1 = mt * 256 + w * 32 + 16 + l16; if (m1 >= count) m1 = count - 1;
    const unsigned short* a0b = xg_t + (size_t)(base + m0) * 8;
    const unsigned short* a1b = xg_t + (size_t)(base + m1) * 8;

    const unsigned short* __restrict__ bimg = pgu + ((size_t)(e * 24 + nt) * 16) * GU_IMG;

#define GU_STAGE(C, BUF) do { \
    const unsigned short* s_ = bimg + (size_t)(C) * GU_IMG + w * 1024 + lane * 8; \
    gld16(s_,       &Bls[BUF][w * 1024]); \
    gld16(s_ + 512, &Bls[BUF][w * 1024 + 512]); } while (0)

    f32x4 accg[2][2], accu[2][2];
#pragma unroll
    for (int i = 0; i < 2; ++i)
#pragma unroll
        for (int f = 0; f < 2; ++f) { accg[i][f] = {0.f,0.f,0.f,0.f}; accu[i][f] = {0.f,0.f,0.f,0.f}; }

    GU_STAGE(0, 0);

    for (int c = 0; c < GU_NC; ++c) {
        const int buf = c & 1;
        __syncthreads();                            // Bls[buf] staged & prior reads done
        if (c + 1 < GU_NC) GU_STAGE(c + 1, buf ^ 1);
#pragma unroll
        for (int s = 0; s < 4; ++s) {
            const size_t aoff = (size_t)(c * 16 + s * 4 + lg) * (S4 * 8);
            bf16x8 a0 = *(const bf16x8*)(a0b + aoff);
            bf16x8 a1 = *(const bf16x8*)(a1b + aoff);
            const unsigned short* bg_ = &Bls[buf][((s * 4 + lg) * 32 + l16) * 8];
            const unsigned short* bu_ = bg_ + 4096;
            bf16x8 g0 = *(const bf16x8*)(bg_);
            bf16x8 g1 = *(const bf16x8*)(bg_ + 128);
            bf16x8 u0 = *(const bf16x8*)(bu_);
            bf16x8 u1 = *(const bf16x8*)(bu_ + 128);
            accg[0][0] = MFMA16(a0, g0, accg[0][0]);
            accg[0][1] = MFMA16(a0, g1, accg[0][1]);
            accu[0][0] = MFMA16(a0, u0, accu[0][0]);
            accu[0][1] = MFMA16(a0, u1, accu[0][1]);
            accg[1][0] = MFMA16(a1, g0, accg[1][0]);
            accg[1][1] = MFMA16(a1, g1, accg[1][1]);
            accu[1][0] = MFMA16(a1, u0, accu[1][0]);
            accu[1][1] = MFMA16(a1, u1, accu[1][1]);
        }
    }
#undef GU_STAGE

#pragma unroll
    for (int i = 0; i < 2; ++i) {
        const int mloc = w * 32 + i * 16 + lg * 4;
#pragma unroll
        for (int r = 0; r < 4; ++r) {
            const int mrow = mt * 256 + mloc + r;
            if (mrow < count) {
                const float wgt = wls[mloc + r];
                const size_t slot = (size_t)(base + mrow);
#pragma unroll
                for (int f = 0; f < 2; ++f) {
                    const int col = nt * 32 + f * 16 + l16;
                    float g = accg[i][f][r], u = accu[i][f][r];
                    float sv = g / (1.f + expf(-g));
                    __hip_bfloat16 hb = __float2bfloat16(wgt * u * sv);
                    h_t[((size_t)(col >> 3) * S4 + slot) * 8 + (col & 7)] = *(unsigned short*)&hb;
                }
            }
        }
    }
}

// ---------------- down MFMA -> slot-major f32 rows (no atomics) ----------------
#define DN_NC (I_DIM / 128)   // 6 chunks
__global__ __launch_bounds__(512, 4) void down_mfma(
    const unsigned short* __restrict__ h_t, const unsigned short* __restrict__ pdn,
    const int* __restrict__ cnt, const int* __restrict__ slot_base,
    float* __restrict__ ods)
{
    const int e  = blockIdx.x;
    const int nt = blockIdx.y;
    const int mt = blockIdx.z;
    const int count = cnt[e];
    if (mt * 256 >= count) return;
    const int tid  = threadIdx.x;
    const int lane = tid & 63;
    const int w    = tid >> 6;
    const int base = slot_base[e];
    const int l16  = lane & 15, lg = lane >> 4;

    __shared__ unsigned short Bls[2][DN_IMG];   // [buf][kk][n64][8] 32KB

    int m0 = mt * 256 + w * 32 + l16;      if (m0 >= count) m0 = count - 1;
    int m1 = mt * 256 + w * 32 + 16 + l16; if (m1 >= count) m1 = count - 1;
    const unsigned short* a0b = h_t + (size_t)(base + m0) * 8;
    const unsigned short* a1b = h_t + (size_t)(base + m1) * 8;

    const unsigned short* __restrict__ bimg = pdn + ((size_t)(e * 32 + nt) * 6) * DN_IMG;

#define DN_STAGE(C, BUF) do { \
    const unsigned short* s_ = bimg + (size_t)(C) * DN_IMG + w * 1024 + lane * 8; \
    gld16(s_,       &Bls[BUF][w * 1024]); \
    gld16(s_ + 512, &Bls[BUF][w * 1024 + 512]); } while (0)

    f32x4 acc[2][4];
#pragma unroll
    for (int i = 0; i < 2; ++i)
#pragma unroll
        for (int f = 0; f < 4; ++f) acc[i][f] = {0.f,0.f,0.f,0.f};

    DN_STAGE(0, 0);

    for (int c = 0; c < DN_NC; ++c) {
        const int buf = c & 1;
        __syncthreads();
        if (c + 1 < DN_NC) DN_STAGE(c + 1, buf ^ 1);
#pragma unroll
        for (int s = 0; s < 4; ++s) {
            const size_t aoff = (size_t)(c * 16 + s * 4 + lg) * (S4 * 8);
            bf16x8 a0 = *(const bf16x8*)(a0b + aoff);
            bf16x8 a1 = *(const bf16x8*)(a1b + aoff);
            const unsigned short* bf_ = &Bls[buf][((s * 4 + lg) * 64 + l16) * 8];
            bf16x8 b0 = *(const bf16x8*)(bf_);
            bf16x8 b1 = *(const bf16x8*)(bf_ + 128);
            bf16x8 b2 = *(const bf16x8*)(bf_ + 256);
            bf16x8 b3 = *(const bf16x8*)(bf_ + 384);
            acc[0][0] = MFMA16(a0, b0, acc[0][0]);
            acc[0][1] = MFMA16(a0, b1, acc[0][1]);
            acc[0][2] = MFMA16(a0, b2, acc[0][2]);
            acc[0][3] = MFMA16(a0, b3, acc[0][3]);
            acc[1][0] = MFMA16(a1, b0, acc[1][0]);
            acc[1][1] = MFMA16(a1, b1, acc[1][1]);
            acc[1][2] = MFMA16(a1, b2, acc[1][2]);
            acc[1][3] = MFMA16(a1, b3, acc[1][3]);
        }
    }
#undef DN_STAGE

#pragma unroll
    for (int i = 0; i < 2; ++i) {
        const int mloc = w * 32 + i * 16 + lg * 4;
#pragma unroll
        for (int r = 0; r < 4; ++r) {
            const int mrow = mt * 256 + mloc + r;
            if (mrow < count) {
                float* orow = ods + (size_t)(base + mrow) * H_DIM + nt * 64;
#pragma unroll
                for (int f = 0; f < 4; ++f)
                    orow[f * 16 + l16] = acc[i][f][r];
            }
        }
    }
}

// ---------------- combine: out[t] = sum of t's 4 slot rows ----------------
__global__ __launch_bounds__(256) void combine_kernel(
    const float* __restrict__ ods, const int* __restrict__ tok_slots,
    const int* __restrict__ slot_base, float* __restrict__ out)
{
    const int t = blockIdx.x;
    const int c0 = threadIdx.x * 8;
    const float* rows[TOPK];
#pragma unroll
    for (int r = 0; r < TOPK; ++r) {
        const int pk = tok_slots[t * TOPK + r];
        const int e = pk >> 12, pos = pk & 4095;
        rows[r] = ods + (size_t)(slot_base[e] + pos) * H_DIM + c0;
    }
    float4 a0 = {0.f,0.f,0.f,0.f}, a1 = {0.f,0.f,0.f,0.f};
#pragma unroll
    for (int r = 0; r < TOPK; ++r) {
        float4 v0 = *(const float4*)(rows[r]);
        float4 v1 = *(const float4*)(rows[r] + 4);
        a0.x += v0.x; a0.y += v0.y; a0.z += v0.z; a0.w += v0.w;
        a1.x += v1.x; a1.y += v1.y; a1.z += v1.z; a1.w += v1.w;
    }
    float* o = out + (size_t)t * H_DIM + c0;
    *(float4*)o = a0;
    *(float4*)(o + 4) = a1;
}

extern "C" void kernel_launch(void* const* d_in, const int* in_sizes, int n_in,
                              void* d_out, int out_size, void* d_ws, size_t ws_size,
                              hipStream_t stream) {
    const float* x      = (const float*)d_in[0];
    const float* gate_w = (const float*)d_in[1];
    const float* gup_w  = (const float*)d_in[2];
    const float* down_w = (const float*)d_in[3];
    float* out    = (float*)d_out;

    char* wsp = (char*)d_ws;
    int*   cnt       = (int*)(wsp);
    int*   slot_base = (int*)(wsp + 256);
    int*   tok_list  = (int*)(wsp + 4096);
    float* tok_w     = (float*)(wsp + 4096 + (size_t)E_NUM * T_TOK * 4);
    int*   tok_slots = (int*)(wsp + (768u << 10));

    size_t off = (size_t)1 << 20;
    unsigned short* xg_t = (unsigned short*)(wsp + off); off += (size_t)S4 * H_DIM * 2;  // 33.6MB
    unsigned short* h_t  = (unsigned short*)(wsp + off); off += (size_t)S4 * I_DIM * 2;  // 12.6MB
    float*          ods  = (float*)(wsp + off);          off += (size_t)S4 * H_DIM * 4;  // 67MB
    unsigned short* pgu  = (unsigned short*)(wsp + off); off += (size_t)E_NUM * 24 * 16 * GU_IMG * 2; // 201MB
    unsigned short* pdn  = (unsigned short*)(wsp + off); off += (size_t)E_NUM * 32 * 6 * DN_IMG * 2;  // 101MB

    hipMemsetAsync(cnt, 0, 256, stream);

    router_kernel<<<T_TOK, 64, 0, stream>>>(x, gate_w, out + (size_t)T_TOK * H_DIM,
                                            cnt, tok_list, tok_w, tok_slots);
    scan_kernel<<<1, 64, 0, stream>>>(cnt, slot_base);
    pack_gu<<<dim3(E_NUM, 256), 256, 0, stream>>>(gup_w, pgu);
    pack_dn<<<dim3(E_NUM, 96), 256, 0, stream>>>(down_w, pdn);
    gather_kernel<<<dim3(E_NUM, 256), 256, 0, stream>>>(x, cnt, slot_base, tok_list, xg_t);
    gateup_mfma<<<dim3(E_NUM, 24, 8), 512, 0, stream>>>(
        xg_t, pgu, cnt, slot_base, tok_w, h_t);
    down_mfma<<<dim3(E_NUM, 32, 8), 512, 0, stream>>>(
        h_t, pdn, cnt, slot_base, ods);
    combine_kernel<<<T_TOK, 256, 0, stream>>>(ods, tok_slots, slot_base, out);
}